// Round 6
// baseline (795.084 us; speedup 1.0000x reference)
//
#include <hip/hip_runtime.h>
#include <float.h>
#include <math.h>

// Problem constants
#define D_REAL 2331   // 259 channels * 3*3 patch
#define D_PAD  2336   // multiple of 32 (MFMA K-tile)
#define N_REAL 7225   // 85*85 patches
#define N_PAD  7296   // 57*128
#define JTILES 57
#define ITILES 57
#define STILES 15     // ceil(57/4) supertile grid per dim
#define KITERS (D_PAD / 32)   // 73 = 1 + 36*2

typedef __attribute__((ext_vector_type(8)))  short bf16x8_t;   // 8 bf16 = 4 VGPRs
typedef __attribute__((ext_vector_type(16))) float f32x16_t;   // 32x32 MFMA C/D

__device__ __forceinline__ unsigned short f2bf(float x) {
    union { float f; unsigned int u; } v; v.f = x;
    unsigned int r = v.u + 0x7FFFu + ((v.u >> 16) & 1u);   // RNE
    return (unsigned short)(r >> 16);
}
__device__ __forceinline__ float bflo(unsigned int u) {
    union { unsigned int x; float f; } v; v.x = u << 16; return v.f;
}
__device__ __forceinline__ float bfhi(unsigned int u) {
    union { unsigned int x; float f; } v; v.x = u & 0xFFFF0000u; return v.f;
}

#define GLOAD_LDS16(g, l) __builtin_amdgcn_global_load_lds( \
    (const __attribute__((address_space(1))) void*)(g),     \
    (__attribute__((address_space(3))) void*)(l), 16, 0, 0)

// ---------------------------------------------------------------------------
// Fused patch-matrix build: resp part (d < 2304) + map part (d in [2304,2336)).
// blockIdx.y selects S or I. bx < 6120: resp tile (u = bx/72, dtile = bx%72);
// else map part.
__global__ __launch_bounds__(256) void build_all(
        const float* __restrict__ respS, const float* __restrict__ respI,
        const float* __restrict__ mapS,  const float* __restrict__ mapI,
        unsigned short* __restrict__ PbS, unsigned short* __restrict__ PbI) {
    const int mat = blockIdx.y;
    unsigned short* Pb = mat ? PbI : PbS;
    const int bx = blockIdx.x;
    if (bx < 6120) {
        const float* resp = mat ? respI : respS;
        __shared__ float slab[5 * 768];        // [cc][rr][col], 15 KB max
        const int u  = bx / 72;                // 0..84
        const int d0 = (bx - u * 72) * 32;     // 0..2272
        const int c0 = d0 / 9;
        const int cN = (d0 + 31) / 9 - c0 + 1; // <= 5
        const int total = cN * 768;
        for (int idx = threadIdx.x; idx < total; idx += 256) {
            int cc = idx / 768;
            int rem = idx - cc * 768;          // (row-3u)*256 + col
            slab[idx] = resp[(((size_t)(c0 + cc)) << 16) + ((size_t)(3 * u) << 8) + rem];
        }
        __syncthreads();
        const int dl = threadIdx.x & 31;
        const int d = d0 + dl;
        const int c = d / 9, r9 = d - c * 9, p = r9 / 3, q = r9 - p * 3;
        const int base = (c - c0) * 768 + p * 256 + q;
        const int v0 = threadIdx.x >> 5;       // 0..7
        size_t out = (size_t)(u * 85) * D_PAD + d0 + dl;
        for (int v = v0; v < 85; v += 8)
            Pb[out + (size_t)v * D_PAD] = f2bf(slab[base + 3 * v]);
    } else {
        const float* map = mat ? mapI : mapS;
        int t = (bx - 6120) * 256 + threadIdx.x;
        int n = t >> 5, dm = t & 31;
        if (n >= N_REAL) return;
        float val = 0.f;
        if (dm < 27) {
            int u = n / 85, v = n - u * 85;
            int ch = dm / 9, r9 = dm - ch * 9, p = r9 / 3, q = r9 - p * 3;
            const float* mp = map + ((size_t)ch << 20)
                                  + ((size_t)((3 * u + p) * 4) << 10)
                                  + (size_t)((3 * v + q) * 4);
            float s = 0.f;
            #pragma unroll
            for (int a = 0; a < 4; a++)
                #pragma unroll
                for (int b = 0; b < 4; b++) s += mp[a * 1024 + b];
            val = 3.125f * s;                  // 50 * (1/16)
        }
        Pb[(size_t)n * D_PAD + 2304 + dm] = f2bf(val);
    }
}

// ---------------------------------------------------------------------------
// sinv[n] = 1/||S[:,n]||; also zeroes loss accumulator + finalize ticket.
__global__ __launch_bounds__(256) void col_norms(const unsigned short* __restrict__ Sb,
                                                 float* __restrict__ sinv,
                                                 double* __restrict__ accum,
                                                 unsigned int* __restrict__ ticket) {
    if (blockIdx.x == 0 && threadIdx.x == 0) { *accum = 0.0; *ticket = 0u; }
    int n = blockIdx.x * 4 + (threadIdx.x >> 6);
    int lane = threadIdx.x & 63;
    const uint4* sp = (const uint4*)(Sb + (size_t)n * D_PAD);
    float s = 0.f;
    for (int k = lane; k < D_PAD / 8; k += 64) {
        uint4 a = sp[k];
        float x0 = bflo(a.x), x1 = bfhi(a.x), x2 = bflo(a.y), x3 = bfhi(a.y);
        float x4 = bflo(a.z), x5 = bfhi(a.z), x6 = bflo(a.w), x7 = bfhi(a.w);
        s = fmaf(x0, x0, s); s = fmaf(x1, x1, s);
        s = fmaf(x2, x2, s); s = fmaf(x3, x3, s);
        s = fmaf(x4, x4, s); s = fmaf(x5, x5, s);
        s = fmaf(x6, x6, s); s = fmaf(x7, x7, s);
    }
    #pragma unroll
    for (int off = 32; off > 0; off >>= 1) s += __shfl_xor(s, off);
    if (lane == 0) sinv[n] = (n < N_REAL) ? rsqrtf(s) : 0.f;
}

// ---------------------------------------------------------------------------
// MFMA GEMM + fused argmax. 32x32x16 bf16 MFMA (2x2 per wave, K=32/iter),
// statically-unrolled double buffer (one barrier per K-tile, all LDS offsets
// compile-time), XOR-swizzled LDS chunks, 4x4 supertile swizzle for L2 reuse.
__global__ __launch_bounds__(256) void gemm_argmax(
        const unsigned short* __restrict__ Sb, const unsigned short* __restrict__ Ib,
        const float* __restrict__ sinv,
        float* __restrict__ pval, int* __restrict__ pidx) {
    const int lb = blockIdx.x;
    const int sup = lb >> 4, win = lb & 15;
    const int it4 = (sup / STILES) * 4 + (win & 3);
    const int jt4 = (sup % STILES) * 4 + (win >> 2);
    if (it4 >= ITILES || jt4 >= JTILES) return;   // uniform: no barrier executed
    const int i0 = it4 * 128, j0 = jt4 * 128;

    __shared__ __align__(16) unsigned short Ash[2][128][32];
    __shared__ __align__(16) unsigned short Bsh[2][128][32];
    const int tid = threadIdx.x;
    const int L = tid & 63, w = tid >> 6;
    const int r32 = L & 31, half = L >> 5;
    const int wi = (w >> 1) * 64, wj = (w & 1) * 64;

    f32x16_t acc[2][2];
    #pragma unroll
    for (int a = 0; a < 2; a++)
        #pragma unroll
        for (int b = 0; b < 2; b++)
            #pragma unroll
            for (int e = 0; e < 16; e++) acc[a][b][e] = 0.f;

    // staging: lane L -> LDS row rl=L>>2, chunk pos L&3; global chunk XOR-swizzled
    const int rl = L >> 2;
    const int ck = (L & 3) ^ ((rl >> 1) & 3);
    const unsigned short* ga = Sb + (size_t)(i0 + w * 32 + rl) * D_PAD + (ck << 3);
    const unsigned short* gb = Ib + (size_t)(j0 + w * 32 + rl) * D_PAD + (ck << 3);

    // read-side: A/B frag for 32x32x16: lane holds row r32, k-chunk `half` (+2 for kh=1)
    // stored chunk = desired ^ ((row>>1)&3); row bases are multiples of 32.
    const int swl = (r32 >> 1) & 3;
    const int c0 = ((half ^ swl) << 3);        // shorts offset, kh=0
    // kh=1 offset = c0 ^ 16 (chunk index ^ 2)

#define PREFETCH(buf) {                                          \
    GLOAD_LDS16(ga,                       &Ash[buf][w*32][0]);   \
    GLOAD_LDS16(ga + (size_t)16 * D_PAD,  &Ash[buf][w*32+16][0]);\
    GLOAD_LDS16(gb,                       &Bsh[buf][w*32][0]);   \
    GLOAD_LDS16(gb + (size_t)16 * D_PAD,  &Bsh[buf][w*32+16][0]);\
    ga += 32; gb += 32; }

#define COMPUTE(buf) {                                                         \
    bf16x8_t a00 = *(const bf16x8_t*)&Ash[buf][wi      + r32][c0];             \
    bf16x8_t a01 = *(const bf16x8_t*)&Ash[buf][wi      + r32][c0 ^ 16];        \
    bf16x8_t a10 = *(const bf16x8_t*)&Ash[buf][wi + 32 + r32][c0];             \
    bf16x8_t a11 = *(const bf16x8_t*)&Ash[buf][wi + 32 + r32][c0 ^ 16];        \
    bf16x8_t b00 = *(const bf16x8_t*)&Bsh[buf][wj      + r32][c0];             \
    bf16x8_t b01 = *(const bf16x8_t*)&Bsh[buf][wj      + r32][c0 ^ 16];        \
    bf16x8_t b10 = *(const bf16x8_t*)&Bsh[buf][wj + 32 + r32][c0];             \
    bf16x8_t b11 = *(const bf16x8_t*)&Bsh[buf][wj + 32 + r32][c0 ^ 16];        \
    acc[0][0] = __builtin_amdgcn_mfma_f32_32x32x16_bf16(a00, b00, acc[0][0], 0, 0, 0); \
    acc[0][1] = __builtin_amdgcn_mfma_f32_32x32x16_bf16(a00, b10, acc[0][1], 0, 0, 0); \
    acc[1][0] = __builtin_amdgcn_mfma_f32_32x32x16_bf16(a10, b00, acc[1][0], 0, 0, 0); \
    acc[1][1] = __builtin_amdgcn_mfma_f32_32x32x16_bf16(a10, b10, acc[1][1], 0, 0, 0); \
    acc[0][0] = __builtin_amdgcn_mfma_f32_32x32x16_bf16(a01, b01, acc[0][0], 0, 0, 0); \
    acc[0][1] = __builtin_amdgcn_mfma_f32_32x32x16_bf16(a01, b11, acc[0][1], 0, 0, 0); \
    acc[1][0] = __builtin_amdgcn_mfma_f32_32x32x16_bf16(a11, b01, acc[1][0], 0, 0, 0); \
    acc[1][1] = __builtin_amdgcn_mfma_f32_32x32x16_bf16(a11, b11, acc[1][1], 0, 0, 0); }

    PREFETCH(0)                                // tile 0 -> buf 0
    for (int p = 0; p < 36; p++) {             // tiles 2p, 2p+1
        __syncthreads();                       // buf0 (tile 2p) ready
        PREFETCH(1)                            // tile 2p+1 -> buf 1
        __builtin_amdgcn_sched_barrier(0);
        COMPUTE(0)
        __syncthreads();                       // buf1 ready
        PREFETCH(0)                            // tile 2p+2 -> buf 0 (max 72)
        __builtin_amdgcn_sched_barrier(0);
        COMPUTE(1)
    }
    __syncthreads();
    COMPUTE(0)                                 // tile 72
#undef PREFETCH
#undef COMPUTE

    // Epilogue. 32x32 C/D: col = lane&31 (j), row = (reg&3)+8*(reg>>2)+4*half (i).
    const int jA = j0 + wj + r32;
    const int jB = jA + 32;
    const float sj0 = sinv[jA], sj1 = sinv[jB];
    const bool mskA = (jA < N_REAL), mskB = (jB < N_REAL);
    #pragma unroll
    for (int mi = 0; mi < 2; mi++) {
        #pragma unroll
        for (int r = 0; r < 16; r++) {
            float v0 = mskA ? acc[mi][0][r] * sj0 : -INFINITY;
            float v1 = mskB ? acc[mi][1][r] * sj1 : -INFINITY;
            float best = v0; int bidx = jA;            // jA < jB: ties keep jA
            if (v1 > best) { best = v1; bidx = jB; }
            #pragma unroll
            for (int off = 1; off < 32; off <<= 1) {   // reduce 32 cols (stay in half)
                float ov = __shfl_xor(best, off);
                int   oi = __shfl_xor(bidx, off);
                if (ov > best || (ov == best && oi < bidx)) { best = ov; bidx = oi; }
            }
            if (r32 == 0) {
                int row = (r & 3) + ((r >> 2) << 3) + (half << 2);
                int i = i0 + wi + mi * 32 + row;
                pval[(size_t)jt4 * N_PAD + i] = best;
                pidx[(size_t)jt4 * N_PAD + i] = bidx;
            }
        }
    }
}

// ---------------------------------------------------------------------------
// Fused merge + loss + finalize. Block = one n: reduce 57 argmax partials,
// accumulate (I[:,n]-S[:,nearest])^2, last block writes the mean to out.
__global__ __launch_bounds__(256) void loss_kernel(
        const unsigned short* __restrict__ Ib, const unsigned short* __restrict__ Sb,
        const float* __restrict__ pval, const int* __restrict__ pidx,
        double* __restrict__ accum, unsigned int* __restrict__ ticket,
        float* __restrict__ out) {
    __shared__ float wsum[4];
    __shared__ int sjn;
    const int n = blockIdx.x;
    if (threadIdx.x < 64) {                    // wave 0: merge 57 partials
        float v = -INFINITY; int id = 0x7fffffff;
        if (threadIdx.x < JTILES) {
            v  = pval[(size_t)threadIdx.x * N_PAD + n];
            id = pidx[(size_t)threadIdx.x * N_PAD + n];
        }
        #pragma unroll
        for (int off = 32; off > 0; off >>= 1) {
            float ov = __shfl_xor(v, off);
            int   oi = __shfl_xor(id, off);
            if (ov > v || (ov == v && oi < id)) { v = ov; id = oi; }
        }
        if (threadIdx.x == 0) sjn = id;
    }
    __syncthreads();
    const int jn = sjn;
    const uint4* ip = (const uint4*)(Ib + (size_t)n  * D_PAD);
    const uint4* sp = (const uint4*)(Sb + (size_t)jn * D_PAD);
    float s = 0.f;
    for (int k = threadIdx.x; k < D_PAD / 8; k += 256) {
        uint4 a = ip[k], b = sp[k];
        float d0 = bflo(a.x) - bflo(b.x), d1 = bfhi(a.x) - bfhi(b.x);
        float d2 = bflo(a.y) - bflo(b.y), d3 = bfhi(a.y) - bfhi(b.y);
        float d4 = bflo(a.z) - bflo(b.z), d5 = bfhi(a.z) - bfhi(b.z);
        float d6 = bflo(a.w) - bflo(b.w), d7 = bfhi(a.w) - bfhi(b.w);
        s = fmaf(d0, d0, s); s = fmaf(d1, d1, s);
        s = fmaf(d2, d2, s); s = fmaf(d3, d3, s);
        s = fmaf(d4, d4, s); s = fmaf(d5, d5, s);
        s = fmaf(d6, d6, s); s = fmaf(d7, d7, s);
    }
    #pragma unroll
    for (int off = 32; off > 0; off >>= 1) s += __shfl_xor(s, off);
    int lane = threadIdx.x & 63, wv = threadIdx.x >> 6;
    if (lane == 0) wsum[wv] = s;
    __syncthreads();
    if (threadIdx.x == 0) {
        double t = (double)wsum[0] + (double)wsum[1] + (double)wsum[2] + (double)wsum[3];
        atomicAdd(accum, t);                   // device-scope
        __threadfence();                       // publish before ticket
        unsigned int prev = atomicAdd(ticket, 1u);
        if (prev == (unsigned int)(gridDim.x - 1)) {
            double v = atomicAdd(accum, 0.0);  // device-scope atomic read
            out[0] = (float)(v / (double)((long long)D_REAL * N_REAL));
        }
    }
}

// ---------------------------------------------------------------------------
extern "C" void kernel_launch(void* const* d_in, const int* in_sizes, int n_in,
                              void* d_out, int out_size, void* d_ws, size_t ws_size,
                              hipStream_t stream) {
    const float* style_resp = (const float*)d_in[0];
    const float* style_map  = (const float*)d_in[1];
    const float* output_map = (const float*)d_in[2];
    const float* model_resp = (const float*)d_in[3];
    float* out = (float*)d_out;

    unsigned short* Sb = (unsigned short*)d_ws;
    unsigned short* Ib = Sb + (size_t)D_PAD * N_PAD;
    float* sinv    = (float*)(Ib + (size_t)D_PAD * N_PAD);
    float* pval    = sinv + N_PAD;
    int*   pidx    = (int*)(pval + (size_t)JTILES * N_PAD);
    double* accum  = (double*)(pidx + (size_t)JTILES * N_PAD);
    unsigned int* ticket = (unsigned int*)(accum + 1);

    // resp tiles: 85*72 = 6120 blocks; map part: ceil(7225*32/256) = 904 blocks
    build_all<<<dim3(6120 + 904, 2), 256, 0, stream>>>(
        style_resp, model_resp, style_map, output_map, Sb, Ib);

    col_norms<<<N_PAD / 4, 256, 0, stream>>>(Sb, sinv, accum, ticket);

    gemm_argmax<<<STILES * STILES * 16, 256, 0, stream>>>(Sb, Ib, sinv, pval, pidx);

    loss_kernel<<<N_REAL, 256, 0, stream>>>(Ib, Sb, pval, pidx, accum, ticket, out);
}

// Round 7
// 628.080 us; speedup vs baseline: 1.2659x; 1.2659x over previous
//
#include <hip/hip_runtime.h>
#include <float.h>
#include <math.h>

// Problem constants
#define D_REAL 2331   // 259 channels * 3*3 patch
#define D_PAD  2336   // multiple of 32 (MFMA K-tile)
#define N_REAL 7225   // 85*85 patches
#define N_PAD  7296   // 57*128
#define JTILES 57
#define ITILES 57
#define STILES 15     // ceil(57/4) supertile grid per dim

typedef __attribute__((ext_vector_type(8))) short bf16x8_t;  // 8 bf16 = 4 VGPRs
typedef __attribute__((ext_vector_type(4))) float f32x4_t;   // 16x16 MFMA C/D

__device__ __forceinline__ unsigned short f2bf(float x) {
    union { float f; unsigned int u; } v; v.f = x;
    unsigned int r = v.u + 0x7FFFu + ((v.u >> 16) & 1u);   // RNE
    return (unsigned short)(r >> 16);
}
__device__ __forceinline__ float bflo(unsigned int u) {
    union { unsigned int x; float f; } v; v.x = u << 16; return v.f;
}
__device__ __forceinline__ float bfhi(unsigned int u) {
    union { unsigned int x; float f; } v; v.x = u & 0xFFFF0000u; return v.f;
}

#define GLOAD_LDS16(g, l) __builtin_amdgcn_global_load_lds( \
    (const __attribute__((address_space(1))) void*)(g),     \
    (__attribute__((address_space(3))) void*)(l), 16, 0, 0)

// ---------------------------------------------------------------------------
// Fused patch-matrix build: resp part (d < 2304) + map part (d in [2304,2336)).
__global__ __launch_bounds__(256) void build_all(
        const float* __restrict__ respS, const float* __restrict__ respI,
        const float* __restrict__ mapS,  const float* __restrict__ mapI,
        unsigned short* __restrict__ PbS, unsigned short* __restrict__ PbI) {
    const int mat = blockIdx.y;
    unsigned short* Pb = mat ? PbI : PbS;
    const int bx = blockIdx.x;
    if (bx < 6120) {
        const float* resp = mat ? respI : respS;
        __shared__ float slab[5 * 768];        // [cc][rr][col], 15 KB max
        const int u  = bx / 72;                // 0..84
        const int d0 = (bx - u * 72) * 32;     // 0..2272
        const int c0 = d0 / 9;
        const int cN = (d0 + 31) / 9 - c0 + 1; // <= 5
        const int total = cN * 768;
        for (int idx = threadIdx.x; idx < total; idx += 256) {
            int cc = idx / 768;
            int rem = idx - cc * 768;          // (row-3u)*256 + col
            slab[idx] = resp[(((size_t)(c0 + cc)) << 16) + ((size_t)(3 * u) << 8) + rem];
        }
        __syncthreads();
        const int dl = threadIdx.x & 31;
        const int d = d0 + dl;
        const int c = d / 9, r9 = d - c * 9, p = r9 / 3, q = r9 - p * 3;
        const int base = (c - c0) * 768 + p * 256 + q;
        const int v0 = threadIdx.x >> 5;       // 0..7
        size_t out = (size_t)(u * 85) * D_PAD + d0 + dl;
        for (int v = v0; v < 85; v += 8)
            Pb[out + (size_t)v * D_PAD] = f2bf(slab[base + 3 * v]);
    } else {
        const float* map = mat ? mapI : mapS;
        int t = (bx - 6120) * 256 + threadIdx.x;
        int n = t >> 5, dm = t & 31;
        if (n >= N_REAL) return;
        float val = 0.f;
        if (dm < 27) {
            int u = n / 85, v = n - u * 85;
            int ch = dm / 9, r9 = dm - ch * 9, p = r9 / 3, q = r9 - p * 3;
            const float* mp = map + ((size_t)ch << 20)
                                  + ((size_t)((3 * u + p) * 4) << 10)
                                  + (size_t)((3 * v + q) * 4);
            float s = 0.f;
            #pragma unroll
            for (int a = 0; a < 4; a++)
                #pragma unroll
                for (int b = 0; b < 4; b++) s += mp[a * 1024 + b];
            val = 3.125f * s;                  // 50 * (1/16)
        }
        Pb[(size_t)n * D_PAD + 2304 + dm] = f2bf(val);
    }
}

// ---------------------------------------------------------------------------
// sinv[n] = 1/||S[:,n]||; also zeroes the loss accumulator.
__global__ __launch_bounds__(256) void col_norms(const unsigned short* __restrict__ Sb,
                                                 float* __restrict__ sinv,
                                                 double* __restrict__ accum) {
    if (blockIdx.x == 0 && threadIdx.x == 0) *accum = 0.0;
    int n = blockIdx.x * 4 + (threadIdx.x >> 6);
    int lane = threadIdx.x & 63;
    const uint4* sp = (const uint4*)(Sb + (size_t)n * D_PAD);
    float s = 0.f;
    for (int k = lane; k < D_PAD / 8; k += 64) {
        uint4 a = sp[k];
        float x0 = bflo(a.x), x1 = bfhi(a.x), x2 = bflo(a.y), x3 = bfhi(a.y);
        float x4 = bflo(a.z), x5 = bfhi(a.z), x6 = bflo(a.w), x7 = bfhi(a.w);
        s = fmaf(x0, x0, s); s = fmaf(x1, x1, s);
        s = fmaf(x2, x2, s); s = fmaf(x3, x3, s);
        s = fmaf(x4, x4, s); s = fmaf(x5, x5, s);
        s = fmaf(x6, x6, s); s = fmaf(x7, x7, s);
    }
    #pragma unroll
    for (int off = 32; off > 0; off >>= 1) s += __shfl_xor(s, off);
    if (lane == 0) sinv[n] = (n < N_REAL) ? rsqrtf(s) : 0.f;
}

// ---------------------------------------------------------------------------
// MFMA GEMM + fused argmax. 16x16x32 bf16 (R5's conflict-free read swizzle,
// measured SQ_LDS_BANK_CONFLICT = 0) + statically-unrolled double buffer
// (R6's VALU win: all LDS offsets compile-time, one barrier per K-tile) +
// 4x4 supertile swizzle for per-XCD L2 reuse.
__global__ __launch_bounds__(256) void gemm_argmax(
        const unsigned short* __restrict__ Sb, const unsigned short* __restrict__ Ib,
        const float* __restrict__ sinv,
        float* __restrict__ pval, int* __restrict__ pidx) {
    const int lb = blockIdx.x;
    const int sup = lb >> 4, win = lb & 15;
    const int it4 = (sup / STILES) * 4 + (win & 3);
    const int jt4 = (sup % STILES) * 4 + (win >> 2);
    if (it4 >= ITILES || jt4 >= JTILES) return;   // uniform: no barrier executed
    const int i0 = it4 * 128, j0 = jt4 * 128;

    __shared__ __align__(16) unsigned short Ash[2][128][32];
    __shared__ __align__(16) unsigned short Bsh[2][128][32];
    const int tid = threadIdx.x;
    const int L = tid & 63, w = tid >> 6;
    const int m = L & 15, q = L >> 4;
    const int wi = (w >> 1) * 64, wj = (w & 1) * 64;

    f32x4_t acc[4][4];
    #pragma unroll
    for (int a = 0; a < 4; a++)
        #pragma unroll
        for (int b = 0; b < 4; b++) acc[a][b] = (f32x4_t){0.f, 0.f, 0.f, 0.f};

    // staging: lane L -> LDS row rl=L>>2, chunk pos L&3; global chunk XOR-swizzled
    const int rl = L >> 2;
    const int ck = (L & 3) ^ ((rl >> 1) & 3);
    const unsigned short* ga = Sb + (size_t)(i0 + w * 32 + rl) * D_PAD + (ck << 3);
    const unsigned short* gb = Ib + (size_t)(j0 + w * 32 + rl) * D_PAD + (ck << 3);

    const int ch = (q ^ ((m >> 1) & 3)) << 3;   // read-side swizzled chunk (R5, 0-conflict)

#define PREFETCH(buf) {                                           \
    GLOAD_LDS16(ga,                       &Ash[buf][w*32][0]);    \
    GLOAD_LDS16(ga + (size_t)16 * D_PAD,  &Ash[buf][w*32+16][0]); \
    GLOAD_LDS16(gb,                       &Bsh[buf][w*32][0]);    \
    GLOAD_LDS16(gb + (size_t)16 * D_PAD,  &Bsh[buf][w*32+16][0]); \
    ga += 32; gb += 32; }

#define COMPUTE(buf) {                                                  \
    bf16x8_t af[4], bfr[4];                                             \
    _Pragma("unroll")                                                   \
    for (int mi = 0; mi < 4; mi++)                                      \
        af[mi] = *(const bf16x8_t*)&Ash[buf][wi + mi * 16 + m][ch];     \
    _Pragma("unroll")                                                   \
    for (int nj = 0; nj < 4; nj++)                                      \
        bfr[nj] = *(const bf16x8_t*)&Bsh[buf][wj + nj * 16 + m][ch];    \
    _Pragma("unroll")                                                   \
    for (int mi = 0; mi < 4; mi++)                                      \
        _Pragma("unroll")                                               \
        for (int nj = 0; nj < 4; nj++)                                  \
            acc[mi][nj] = __builtin_amdgcn_mfma_f32_16x16x32_bf16(      \
                af[mi], bfr[nj], acc[mi][nj], 0, 0, 0); }

    PREFETCH(0)                                // tile 0 -> buf 0
    for (int p = 0; p < 36; p++) {             // tiles 2p, 2p+1
        __syncthreads();                       // buf0 (tile 2p) ready
        PREFETCH(1)                            // tile 2p+1 -> buf 1
        __builtin_amdgcn_sched_barrier(0);
        COMPUTE(0)
        __syncthreads();                       // buf1 ready
        PREFETCH(0)                            // tile 2p+2 -> buf 0 (max 72)
        __builtin_amdgcn_sched_barrier(0);
        COMPUTE(1)
    }
    __syncthreads();
    COMPUTE(0)                                 // tile 72
#undef PREFETCH
#undef COMPUTE

    // Epilogue. C/D layout: col = m (j-dir), row = q*4 + reg (i-dir).
    float sjv[4];
    #pragma unroll
    for (int nj = 0; nj < 4; nj++) sjv[nj] = sinv[j0 + wj + nj * 16 + m];
    #pragma unroll
    for (int mi = 0; mi < 4; mi++) {
        #pragma unroll
        for (int r = 0; r < 4; r++) {
            float best = -INFINITY; int bidx = 0x7fffffff;
            #pragma unroll
            for (int nj = 0; nj < 4; nj++) {   // j ascending -> '>' keeps smallest
                int j = j0 + wj + nj * 16 + m;
                float v = (j < N_REAL) ? acc[mi][nj][r] * sjv[nj] : -INFINITY;
                if (v > best) { best = v; bidx = j; }
            }
            #pragma unroll
            for (int off = 1; off < 16; off <<= 1) {
                float ov = __shfl_xor(best, off);
                int   oi = __shfl_xor(bidx, off);
                if (ov > best || (ov == best && oi < bidx)) { best = ov; bidx = oi; }
            }
            if (m == 0) {
                int i = i0 + wi + mi * 16 + q * 4 + r;
                pval[(size_t)jt4 * N_PAD + i] = best;
                pidx[(size_t)jt4 * N_PAD + i] = bidx;
            }
        }
    }
}

// ---------------------------------------------------------------------------
// Fused merge + loss. Block = one n: reduce the 57 per-j-tile argmax
// partials in-wave, then accumulate (I[:,n] - S[:,nearest])^2.
__global__ __launch_bounds__(256) void loss_kernel(
        const unsigned short* __restrict__ Ib, const unsigned short* __restrict__ Sb,
        const float* __restrict__ pval, const int* __restrict__ pidx,
        double* __restrict__ accum) {
    __shared__ float wsum[4];
    __shared__ int sjn;
    const int n = blockIdx.x;
    if (threadIdx.x < 64) {                    // wave 0: merge 57 partials
        float v = -INFINITY; int id = 0x7fffffff;
        if (threadIdx.x < JTILES) {
            v  = pval[(size_t)threadIdx.x * N_PAD + n];
            id = pidx[(size_t)threadIdx.x * N_PAD + n];
        }
        #pragma unroll
        for (int off = 32; off > 0; off >>= 1) {
            float ov = __shfl_xor(v, off);
            int   oi = __shfl_xor(id, off);
            if (ov > v || (ov == v && oi < id)) { v = ov; id = oi; }
        }
        if (threadIdx.x == 0) sjn = id;
    }
    __syncthreads();
    const int jn = sjn;
    const uint4* ip = (const uint4*)(Ib + (size_t)n  * D_PAD);
    const uint4* sp = (const uint4*)(Sb + (size_t)jn * D_PAD);
    float s = 0.f;
    for (int k = threadIdx.x; k < D_PAD / 8; k += 256) {
        uint4 a = ip[k], b = sp[k];
        float d0 = bflo(a.x) - bflo(b.x), d1 = bfhi(a.x) - bfhi(b.x);
        float d2 = bflo(a.y) - bflo(b.y), d3 = bfhi(a.y) - bfhi(b.y);
        float d4 = bflo(a.z) - bflo(b.z), d5 = bfhi(a.z) - bfhi(b.z);
        float d6 = bflo(a.w) - bflo(b.w), d7 = bfhi(a.w) - bfhi(b.w);
        s = fmaf(d0, d0, s); s = fmaf(d1, d1, s);
        s = fmaf(d2, d2, s); s = fmaf(d3, d3, s);
        s = fmaf(d4, d4, s); s = fmaf(d5, d5, s);
        s = fmaf(d6, d6, s); s = fmaf(d7, d7, s);
    }
    #pragma unroll
    for (int off = 32; off > 0; off >>= 1) s += __shfl_xor(s, off);
    int lane = threadIdx.x & 63, wv = threadIdx.x >> 6;
    if (lane == 0) wsum[wv] = s;
    __syncthreads();
    if (threadIdx.x == 0) {
        double t = (double)wsum[0] + (double)wsum[1] + (double)wsum[2] + (double)wsum[3];
        atomicAdd(accum, t);
    }
}

__global__ void finalize(const double* __restrict__ accum, float* __restrict__ out) {
    out[0] = (float)(accum[0] / (double)((long long)D_REAL * N_REAL));
}

// ---------------------------------------------------------------------------
extern "C" void kernel_launch(void* const* d_in, const int* in_sizes, int n_in,
                              void* d_out, int out_size, void* d_ws, size_t ws_size,
                              hipStream_t stream) {
    const float* style_resp = (const float*)d_in[0];
    const float* style_map  = (const float*)d_in[1];
    const float* output_map = (const float*)d_in[2];
    const float* model_resp = (const float*)d_in[3];
    float* out = (float*)d_out;

    unsigned short* Sb = (unsigned short*)d_ws;
    unsigned short* Ib = Sb + (size_t)D_PAD * N_PAD;
    float* sinv    = (float*)(Ib + (size_t)D_PAD * N_PAD);
    float* pval    = sinv + N_PAD;
    int*   pidx    = (int*)(pval + (size_t)JTILES * N_PAD);
    double* accum  = (double*)(pidx + (size_t)JTILES * N_PAD);

    // resp tiles: 85*72 = 6120 blocks; map part: ceil(7225*32/256) = 904 blocks
    build_all<<<dim3(6120 + 904, 2), 256, 0, stream>>>(
        style_resp, model_resp, style_map, output_map, Sb, Ib);

    col_norms<<<N_PAD / 4, 256, 0, stream>>>(Sb, sinv, accum);

    gemm_argmax<<<STILES * STILES * 16, 256, 0, stream>>>(Sb, Ib, sinv, pval, pidx);

    loss_kernel<<<N_REAL, 256, 0, stream>>>(Ib, Sb, pval, pidx, accum);
    finalize<<<1, 1, 0, stream>>>(accum, out);
}

// Round 8
// 492.024 us; speedup vs baseline: 1.6159x; 1.2765x over previous
//
#include <hip/hip_runtime.h>
#include <float.h>
#include <math.h>

// Problem constants
#define D_REAL 2331   // 259 channels * 3*3 patch
#define D_PAD  2336   // bf16 matrix row length
#define DQ     2304   // fp8 matrix row length (resp dims only; 18*128)
#define N_REAL 7225   // 85*85 patches
#define N_PAD  7296   // 57*128
#define JTILES 57
#define ITILES 57
#define STILES 15     // ceil(57/4) supertile grid per dim

typedef __attribute__((ext_vector_type(8))) short bf16x8_t;  // 8 bf16 = 4 VGPRs
typedef __attribute__((ext_vector_type(4))) float f32x4_t;   // 16x16 MFMA C/D
typedef __attribute__((ext_vector_type(8))) int   v8i_t;     // MX A/B operand
typedef __attribute__((ext_vector_type(4))) int   v4i_t;

__device__ __forceinline__ unsigned short f2bf(float x) {
    union { float f; unsigned int u; } v; v.f = x;
    unsigned int r = v.u + 0x7FFFu + ((v.u >> 16) & 1u);   // RNE
    return (unsigned short)(r >> 16);
}
__device__ __forceinline__ float bflo(unsigned int u) {
    union { unsigned int x; float f; } v; v.x = u << 16; return v.f;
}
__device__ __forceinline__ float bfhi(unsigned int u) {
    union { unsigned int x; float f; } v; v.x = u & 0xFFFF0000u; return v.f;
}

#define GLOAD_LDS16(g, l) __builtin_amdgcn_global_load_lds( \
    (const __attribute__((address_space(1))) void*)(g),     \
    (__attribute__((address_space(3))) void*)(l), 16, 0, 0)

// ---------------------------------------------------------------------------
// Fused build: resp part -> bf16 Pb[n][0..2304) AND fp8 Pq[n][0..2304);
// map part -> bf16 Pb[n][2304..2336) only (50 * avgpool4 + zero pad).
__global__ __launch_bounds__(256) void build_all(
        const float* __restrict__ respS, const float* __restrict__ respI,
        const float* __restrict__ mapS,  const float* __restrict__ mapI,
        unsigned short* __restrict__ PbS, unsigned short* __restrict__ PbI,
        unsigned char* __restrict__ PqS, unsigned char* __restrict__ PqI) {
    const int mat = blockIdx.y;
    unsigned short* Pb = mat ? PbI : PbS;
    const int bx = blockIdx.x;
    if (bx < 6120) {
        const float* resp = mat ? respI : respS;
        unsigned char* Pq = mat ? PqI : PqS;
        __shared__ float slab[5 * 768];        // [cc][rr][col], 15 KB max
        const int u  = bx / 72;                // 0..84
        const int d0 = (bx - u * 72) * 32;     // 0..2272
        const int c0 = d0 / 9;
        const int cN = (d0 + 31) / 9 - c0 + 1; // <= 5
        const int total = cN * 768;
        for (int idx = threadIdx.x; idx < total; idx += 256) {
            int cc = idx / 768;
            int rem = idx - cc * 768;          // (row-3u)*256 + col
            slab[idx] = resp[(((size_t)(c0 + cc)) << 16) + ((size_t)(3 * u) << 8) + rem];
        }
        __syncthreads();
        const int dl16 = threadIdx.x & 15;     // d-pair index
        const int de = d0 + 2 * dl16, dq = de + 1;
        const int ce = de / 9, re = de - ce * 9, pe = re / 3, qe = re - pe * 3;
        const int co = dq / 9, ro = dq - co * 9, po = ro / 3, qo = ro - po * 3;
        const int base_e = (ce - c0) * 768 + pe * 256 + qe;
        const int base_o = (co - c0) * 768 + po * 256 + qo;
        const int v0 = threadIdx.x >> 4;       // 0..15
        for (int v = v0; v < 85; v += 16) {
            float x0 = slab[base_e + 3 * v];
            float x1 = slab[base_o + 3 * v];
            size_t row = (size_t)(u * 85 + v);
            *(unsigned int*)&Pb[row * D_PAD + de] =
                (unsigned int)f2bf(x0) | ((unsigned int)f2bf(x1) << 16);
            int pk = __builtin_amdgcn_cvt_pk_fp8_f32(x0, x1, 0, false);
            *(unsigned short*)&Pq[row * DQ + de] = (unsigned short)pk;
        }
    } else {
        const float* map = mat ? mapI : mapS;
        int t = (bx - 6120) * 256 + threadIdx.x;
        int n = t >> 5, dm = t & 31;
        if (n >= N_REAL) return;
        float val = 0.f;
        if (dm < 27) {
            int u = n / 85, v = n - u * 85;
            int ch = dm / 9, r9 = dm - ch * 9, p = r9 / 3, q = r9 - p * 3;
            const float* mp = map + ((size_t)ch << 20)
                                  + ((size_t)((3 * u + p) * 4) << 10)
                                  + (size_t)((3 * v + q) * 4);
            float s = 0.f;
            #pragma unroll
            for (int a = 0; a < 4; a++)
                #pragma unroll
                for (int b = 0; b < 4; b++) s += mp[a * 1024 + b];
            val = 3.125f * s;                  // 50 * (1/16)
        }
        Pb[(size_t)n * D_PAD + 2304 + dm] = f2bf(val);
    }
}

// ---------------------------------------------------------------------------
// sinv[n] = 1/||S[:,n]|| (bf16 matrix); also zeroes the loss accumulator.
__global__ __launch_bounds__(256) void col_norms(const unsigned short* __restrict__ Sb,
                                                 float* __restrict__ sinv,
                                                 double* __restrict__ accum) {
    if (blockIdx.x == 0 && threadIdx.x == 0) *accum = 0.0;
    int n = blockIdx.x * 4 + (threadIdx.x >> 6);
    int lane = threadIdx.x & 63;
    const uint4* sp = (const uint4*)(Sb + (size_t)n * D_PAD);
    float s = 0.f;
    for (int k = lane; k < D_PAD / 8; k += 64) {
        uint4 a = sp[k];
        float x0 = bflo(a.x), x1 = bfhi(a.x), x2 = bflo(a.y), x3 = bfhi(a.y);
        float x4 = bflo(a.z), x5 = bfhi(a.z), x6 = bflo(a.w), x7 = bfhi(a.w);
        s = fmaf(x0, x0, s); s = fmaf(x1, x1, s);
        s = fmaf(x2, x2, s); s = fmaf(x3, x3, s);
        s = fmaf(x4, x4, s); s = fmaf(x5, x5, s);
        s = fmaf(x6, x6, s); s = fmaf(x7, x7, s);
    }
    #pragma unroll
    for (int off = 32; off > 0; off >>= 1) s += __shfl_xor(s, off);
    if (lane == 0) sinv[n] = (n < N_REAL) ? rsqrtf(s) : 0.f;
}

// ---------------------------------------------------------------------------
// MX-fp8 GEMM + fused argmax. K split: 18 x (16x16x128 f8f6f4, unit scales)
// over the resp dims + 1 x (16x16x32 bf16) tail over the 50x-weighted map
// dims (same f32 acc; C/D layout dtype-independent). Double-buffered 16KB
// fp8 tiles (64KB LDS, one barrier per K-tile), XOR chunk swizzle, 4x4
// supertile swizzle. Loss-relevant precision lives in the bf16 tail; fp8
// noise on resp dims is ~sigma 1.4 vs ~470 candidate spread.
__global__ __launch_bounds__(256) void gemm_argmax(
        const unsigned char* __restrict__ Sq, const unsigned char* __restrict__ Iq,
        const unsigned short* __restrict__ Sb, const unsigned short* __restrict__ Ib,
        const float* __restrict__ sinv,
        float* __restrict__ pval, int* __restrict__ pidx) {
    const int lb = blockIdx.x;
    const int sup = lb >> 4, win = lb & 15;
    const int it4 = (sup / STILES) * 4 + (win & 3);
    const int jt4 = (sup % STILES) * 4 + (win >> 2);
    if (it4 >= ITILES || jt4 >= JTILES) return;   // uniform: no barrier executed
    const int i0 = it4 * 128, j0 = jt4 * 128;

    __shared__ __align__(16) unsigned char Af[2][128][128];   // 32 KB
    __shared__ __align__(16) unsigned char Bf[2][128][128];   // 32 KB
    const int tid = threadIdx.x;
    const int L = tid & 63, w = tid >> 6;
    const int m = L & 15, q = L >> 4;
    const int wi = (w >> 1) * 64, wj = (w & 1) * 64;

    f32x4_t acc[4][4];
    #pragma unroll
    for (int a = 0; a < 4; a++)
        #pragma unroll
        for (int b = 0; b < 4; b++) acc[a][b] = (f32x4_t){0.f, 0.f, 0.f, 0.f};

    // fp8 staging: lane L -> LDS row rl = L>>3 (128B rows), chunk pos L&7;
    // global 16B chunk ck = (L&7) ^ (rl&7)  (XOR involution, spreads banks).
    const int rl = L >> 3;
    const int ck = (L & 7) ^ rl;
    const unsigned char* gqa = Sq + (size_t)(i0 + w * 32 + rl) * DQ + (ck << 4);
    const unsigned char* gqb = Iq + (size_t)(j0 + w * 32 + rl) * DQ + (ck << 4);

    // read-side swizzled 16B-chunk byte offsets (row r: stored = c ^ (r&7); r&7 == m&7)
    const int clo = ((((q << 1))     ^ (m & 7)) << 4);
    const int chi = ((((q << 1) | 1) ^ (m & 7)) << 4);

    // bf16 tail staging (R7 pattern), overlaid on buffer-0 regions (8KB each)
    unsigned short (*At)[32] = (unsigned short(*)[32])&Af[0][0][0];
    unsigned short (*Bt)[32] = (unsigned short(*)[32])&Bf[0][0][0];
    const int rl2 = L >> 2;
    const int ck2 = (L & 3) ^ ((rl2 >> 1) & 3);
    const unsigned short* gta = Sb + (size_t)(i0 + w * 32 + rl2) * D_PAD + 2304 + (ck2 << 3);
    const unsigned short* gtb = Ib + (size_t)(j0 + w * 32 + rl2) * D_PAD + 2304 + (ck2 << 3);
    const int cht = (q ^ ((m >> 1) & 3)) << 3;   // tail read chunk (shorts)

#define PREFETCH_Q(buf) {                                     \
    GLOAD_LDS16(gqa,             &Af[buf][w * 32     ][0]);   \
    GLOAD_LDS16(gqa +  8 * DQ,   &Af[buf][w * 32 +  8][0]);   \
    GLOAD_LDS16(gqa + 16 * DQ,   &Af[buf][w * 32 + 16][0]);   \
    GLOAD_LDS16(gqa + 24 * DQ,   &Af[buf][w * 32 + 24][0]);   \
    GLOAD_LDS16(gqb,             &Bf[buf][w * 32     ][0]);   \
    GLOAD_LDS16(gqb +  8 * DQ,   &Bf[buf][w * 32 +  8][0]);   \
    GLOAD_LDS16(gqb + 16 * DQ,   &Bf[buf][w * 32 + 16][0]);   \
    GLOAD_LDS16(gqb + 24 * DQ,   &Bf[buf][w * 32 + 24][0]);   \
    gqa += 128; gqb += 128; }

#define COMPUTE_Q(buf) {                                                   \
    v8i_t aq[4], bq[4];                                                    \
    _Pragma("unroll")                                                      \
    for (int mi = 0; mi < 4; mi++) {                                       \
        v4i_t lo = *(const v4i_t*)&Af[buf][wi + mi * 16 + m][clo];         \
        v4i_t hi = *(const v4i_t*)&Af[buf][wi + mi * 16 + m][chi];         \
        aq[mi] = __builtin_shufflevector(lo, hi, 0, 1, 2, 3, 4, 5, 6, 7);  \
    }                                                                      \
    _Pragma("unroll")                                                      \
    for (int nj = 0; nj < 4; nj++) {                                       \
        v4i_t lo = *(const v4i_t*)&Bf[buf][wj + nj * 16 + m][clo];         \
        v4i_t hi = *(const v4i_t*)&Bf[buf][wj + nj * 16 + m][chi];         \
        bq[nj] = __builtin_shufflevector(lo, hi, 0, 1, 2, 3, 4, 5, 6, 7);  \
    }                                                                      \
    _Pragma("unroll")                                                      \
    for (int mi = 0; mi < 4; mi++)                                         \
        _Pragma("unroll")                                                  \
        for (int nj = 0; nj < 4; nj++)                                     \
            acc[mi][nj] = __builtin_amdgcn_mfma_scale_f32_16x16x128_f8f6f4(\
                aq[mi], bq[nj], acc[mi][nj], 0, 0, 0, 0x7F, 0, 0x7F); }

    PREFETCH_Q(0)                              // fp8 tile 0 -> buf 0
    for (int p = 0; p < 8; p++) {              // fp8 tiles 0..15
        __syncthreads();
        PREFETCH_Q(1)
        __builtin_amdgcn_sched_barrier(0);
        COMPUTE_Q(0)
        __syncthreads();
        PREFETCH_Q(0)
        __builtin_amdgcn_sched_barrier(0);
        COMPUTE_Q(1)
    }
    __syncthreads();
    PREFETCH_Q(1)                              // fp8 tile 17
    __builtin_amdgcn_sched_barrier(0);
    COMPUTE_Q(0)                               // fp8 tile 16
    __syncthreads();
    {                                          // bf16 map-dim tail -> buf0 overlay
        GLOAD_LDS16(gta,                      &At[w * 32][0]);
        GLOAD_LDS16(gta + (size_t)16 * D_PAD, &At[w * 32 + 16][0]);
        GLOAD_LDS16(gtb,                      &Bt[w * 32][0]);
        GLOAD_LDS16(gtb + (size_t)16 * D_PAD, &Bt[w * 32 + 16][0]);
    }
    __builtin_amdgcn_sched_barrier(0);
    COMPUTE_Q(1)                               // fp8 tile 17
    __syncthreads();                           // tail tiles ready
    {
        bf16x8_t af[4], bfr[4];
        #pragma unroll
        for (int mi = 0; mi < 4; mi++)
            af[mi] = *(const bf16x8_t*)&At[wi + mi * 16 + m][cht];
        #pragma unroll
        for (int nj = 0; nj < 4; nj++)
            bfr[nj] = *(const bf16x8_t*)&Bt[wj + nj * 16 + m][cht];
        #pragma unroll
        for (int mi = 0; mi < 4; mi++)
            #pragma unroll
            for (int nj = 0; nj < 4; nj++)
                acc[mi][nj] = __builtin_amdgcn_mfma_f32_16x16x32_bf16(
                    af[mi], bfr[nj], acc[mi][nj], 0, 0, 0);
    }
#undef PREFETCH_Q
#undef COMPUTE_Q

    // Epilogue. C/D layout: col = m (j-dir), row = q*4 + reg (i-dir).
    float sjv[4];
    #pragma unroll
    for (int nj = 0; nj < 4; nj++) sjv[nj] = sinv[j0 + wj + nj * 16 + m];
    #pragma unroll
    for (int mi = 0; mi < 4; mi++) {
        #pragma unroll
        for (int r = 0; r < 4; r++) {
            float best = -INFINITY; int bidx = 0x7fffffff;
            #pragma unroll
            for (int nj = 0; nj < 4; nj++) {   // j ascending -> '>' keeps smallest
                int j = j0 + wj + nj * 16 + m;
                float v = (j < N_REAL) ? acc[mi][nj][r] * sjv[nj] : -INFINITY;
                if (v > best) { best = v; bidx = j; }
            }
            #pragma unroll
            for (int off = 1; off < 16; off <<= 1) {
                float ov = __shfl_xor(best, off);
                int   oi = __shfl_xor(bidx, off);
                if (ov > best || (ov == best && oi < bidx)) { best = ov; bidx = oi; }
            }
            if (m == 0) {
                int i = i0 + wi + mi * 16 + q * 4 + r;
                pval[(size_t)jt4 * N_PAD + i] = best;
                pidx[(size_t)jt4 * N_PAD + i] = bidx;
            }
        }
    }
}

// ---------------------------------------------------------------------------
// Fused merge + loss (reads bf16 matrices -> precision as R2-R7).
__global__ __launch_bounds__(256) void loss_kernel(
        const unsigned short* __restrict__ Ib, const unsigned short* __restrict__ Sb,
        const float* __restrict__ pval, const int* __restrict__ pidx,
        double* __restrict__ accum) {
    __shared__ float wsum[4];
    __shared__ int sjn;
    const int n = blockIdx.x;
    if (threadIdx.x < 64) {                    // wave 0: merge 57 partials
        float v = -INFINITY; int id = 0x7fffffff;
        if (threadIdx.x < JTILES) {
            v  = pval[(size_t)threadIdx.x * N_PAD + n];
            id = pidx[(size_t)threadIdx.x * N_PAD + n];
        }
        #pragma unroll
        for (int off = 32; off > 0; off >>= 1) {
            float ov = __shfl_xor(v, off);
            int   oi = __shfl_xor(id, off);
            if (ov > v || (ov == v && oi < id)) { v = ov; id = oi; }
        }
        if (threadIdx.x == 0) sjn = id;
    }
    __syncthreads();
    const int jn = sjn;
    const uint4* ip = (const uint4*)(Ib + (size_t)n  * D_PAD);
    const uint4* sp = (const uint4*)(Sb + (size_t)jn * D_PAD);
    float s = 0.f;
    for (int k = threadIdx.x; k < D_PAD / 8; k += 256) {
        uint4 a = ip[k], b = sp[k];
        float d0 = bflo(a.x) - bflo(b.x), d1 = bfhi(a.x) - bfhi(b.x);
        float d2 = bflo(a.y) - bflo(b.y), d3 = bfhi(a.y) - bfhi(b.y);
        float d4 = bflo(a.z) - bflo(b.z), d5 = bfhi(a.z) - bfhi(b.z);
        float d6 = bflo(a.w) - bflo(b.w), d7 = bfhi(a.w) - bfhi(b.w);
        s = fmaf(d0, d0, s); s = fmaf(d1, d1, s);
        s = fmaf(d2, d2, s); s = fmaf(d3, d3, s);
        s = fmaf(d4, d4, s); s = fmaf(d5, d5, s);
        s = fmaf(d6, d6, s); s = fmaf(d7, d7, s);
    }
    #pragma unroll
    for (int off = 32; off > 0; off >>= 1) s += __shfl_xor(s, off);
    int lane = threadIdx.x & 63, wv = threadIdx.x >> 6;
    if (lane == 0) wsum[wv] = s;
    __syncthreads();
    if (threadIdx.x == 0) {
        double t = (double)wsum[0] + (double)wsum[1] + (double)wsum[2] + (double)wsum[3];
        atomicAdd(accum, t);
    }
}

__global__ void finalize(const double* __restrict__ accum, float* __restrict__ out) {
    out[0] = (float)(accum[0] / (double)((long long)D_REAL * N_REAL));
}

// ---------------------------------------------------------------------------
extern "C" void kernel_launch(void* const* d_in, const int* in_sizes, int n_in,
                              void* d_out, int out_size, void* d_ws, size_t ws_size,
                              hipStream_t stream) {
    const float* style_resp = (const float*)d_in[0];
    const float* style_map  = (const float*)d_in[1];
    const float* output_map = (const float*)d_in[2];
    const float* model_resp = (const float*)d_in[3];
    float* out = (float*)d_out;

    unsigned short* Sb = (unsigned short*)d_ws;
    unsigned short* Ib = Sb + (size_t)D_PAD * N_PAD;
    unsigned char*  Sq = (unsigned char*)(Ib + (size_t)D_PAD * N_PAD);
    unsigned char*  Iq = Sq + (size_t)DQ * N_PAD;
    float* sinv    = (float*)(Iq + (size_t)DQ * N_PAD);
    float* pval    = sinv + N_PAD;
    int*   pidx    = (int*)(pval + (size_t)JTILES * N_PAD);
    double* accum  = (double*)(pidx + (size_t)JTILES * N_PAD);

    // resp tiles: 85*72 = 6120 blocks; map part: ceil(7225*32/256) = 904 blocks
    build_all<<<dim3(6120 + 904, 2), 256, 0, stream>>>(
        style_resp, model_resp, style_map, output_map, Sb, Ib, Sq, Iq);

    col_norms<<<N_PAD / 4, 256, 0, stream>>>(Sb, sinv, accum);

    gemm_argmax<<<STILES * STILES * 16, 256, 0, stream>>>(Sq, Iq, Sb, Ib, sinv, pval, pidx);

    loss_kernel<<<N_REAL, 256, 0, stream>>>(Ib, Sb, pval, pidx, accum);
    finalize<<<1, 1, 0, stream>>>(accum, out);
}